// Round 1
// baseline (406.897 us; speedup 1.0000x reference)
//
#include <hip/hip_runtime.h>
#include <cstddef>

#define NSTATE 1280
#define TCACHE 448
#define NBATCH 128
#define NHEAD  20
#define HDIM   64

// ---------------------------------------------------------------------------
// fp32 tiled GEMM body: C[m][n] = A[128][1280] @ B[1280][1280] (+ bias)
// BM=64, BN=32, BK=32, 256 threads, per-thread micro-tile 4x2.
// C row stride ldc parameterized so k/v projections can write directly into
// the final row (t=447) of the output caches.
// ---------------------------------------------------------------------------
__device__ __forceinline__ void gemm_body(const float* __restrict__ A,
                                          const float* __restrict__ B,
                                          const float* __restrict__ bias,
                                          float* __restrict__ C, size_t ldc)
{
    __shared__ float As[32][64];   // [k][m] (transposed for float4 m-reads)
    __shared__ float Bs[32][32];   // [k][n]
    const int tid = threadIdx.x;
    const int m0 = blockIdx.y * 64;
    const int n0 = blockIdx.x * 32;
    const int tr = tid >> 4;       // 0..15 -> rows tr*4..tr*4+3
    const int tc = tid & 15;       // 0..15 -> cols tc*2, tc*2+1
    float acc[4][2] = {{0.f,0.f},{0.f,0.f},{0.f,0.f},{0.f,0.f}};

    for (int k0 = 0; k0 < NSTATE; k0 += 32) {
        // A tile: 64 rows x 32 k = 2048 floats; 256 thr x 2 float4, transpose into LDS
        #pragma unroll
        for (int j = 0; j < 2; ++j) {
            int chunk = tid * 2 + j;           // 0..511
            int row   = chunk >> 3;            // 0..63
            int kc    = (chunk & 7) << 2;      // 0,4,..,28
            float4 a = *(const float4*)(A + (size_t)(m0 + row) * NSTATE + k0 + kc);
            As[kc+0][row] = a.x; As[kc+1][row] = a.y;
            As[kc+2][row] = a.z; As[kc+3][row] = a.w;
        }
        // B tile: 32 k x 32 n = 1024 floats; 256 thr x 1 float4
        {
            int row = tid >> 3;                // 0..31 (k)
            int nc  = (tid & 7) << 2;          // 0..28
            float4 b4 = *(const float4*)(B + (size_t)(k0 + row) * NSTATE + n0 + nc);
            *(float4*)&Bs[row][nc] = b4;
        }
        __syncthreads();
        #pragma unroll
        for (int kk = 0; kk < 32; ++kk) {
            float4 a = *(const float4*)&As[kk][tr << 2];
            float2 b = *(const float2*)&Bs[kk][tc << 1];
            acc[0][0] = fmaf(a.x, b.x, acc[0][0]); acc[0][1] = fmaf(a.x, b.y, acc[0][1]);
            acc[1][0] = fmaf(a.y, b.x, acc[1][0]); acc[1][1] = fmaf(a.y, b.y, acc[1][1]);
            acc[2][0] = fmaf(a.z, b.x, acc[2][0]); acc[2][1] = fmaf(a.z, b.y, acc[2][1]);
            acc[3][0] = fmaf(a.w, b.x, acc[3][0]); acc[3][1] = fmaf(a.w, b.y, acc[3][1]);
        }
        __syncthreads();
    }
    const int n = n0 + (tc << 1);
    const float b0 = bias ? bias[n]   : 0.f;
    const float b1 = bias ? bias[n+1] : 0.f;
    #pragma unroll
    for (int i = 0; i < 4; ++i) {
        size_t m = (size_t)(m0 + (tr << 2) + i);
        C[m * ldc + n]     = acc[i][0] + b0;
        C[m * ldc + n + 1] = acc[i][1] + b1;
    }
}

// QKV projection. grid (40, 2, 3): z=0 -> q (ws), z=1 -> k row447 of kout,
// z=2 -> v row447 of vout. Whisper: k has no bias.
__global__ void __launch_bounds__(256) qkv_kernel(
    const float* __restrict__ x,
    const float* __restrict__ Wq, const float* __restrict__ bq,
    const float* __restrict__ Wk,
    const float* __restrict__ Wv, const float* __restrict__ bv,
    float* __restrict__ q_ws, float* __restrict__ kout, float* __restrict__ vout)
{
    const int z = blockIdx.z;
    const float* B    = (z == 0) ? Wq : (z == 1 ? Wk : Wv);
    const float* bias = (z == 0) ? bq : (z == 1 ? nullptr : bv);
    float* C;
    size_t ldc;
    if (z == 0)      { C = q_ws;                                  ldc = NSTATE; }
    else if (z == 1) { C = kout + (size_t)(TCACHE-1) * NSTATE;    ldc = (size_t)TCACHE * NSTATE; }
    else             { C = vout + (size_t)(TCACHE-1) * NSTATE;    ldc = (size_t)TCACHE * NSTATE; }
    gemm_body(x, B, bias, C, ldc);
}

// Output projection. grid (40, 2).
__global__ void __launch_bounds__(256) outproj_kernel(
    const float* __restrict__ wv, const float* __restrict__ Wo,
    const float* __restrict__ bo, float* __restrict__ out)
{
    gemm_body(wv, Wo, bo, out, NSTATE);
}

// ---------------------------------------------------------------------------
// Fused cache-shift + attention. grid (20 heads, 128 batch), 256 threads
// (4 waves). Each block handles the [b, :, h*64:(h+1)*64] slice of both
// caches: K pass does shift-copy + QK^T scores, then softmax, then V pass
// does shift-copy + PV accumulate. Row 447 was already written by qkv_kernel.
// ---------------------------------------------------------------------------
__global__ void __launch_bounds__(256) attn_kernel(
    const float* __restrict__ kin, const float* __restrict__ vin,
    const float* __restrict__ q_ws, const float* __restrict__ mask,
    float* __restrict__ kout, float* __restrict__ vout,
    float* __restrict__ wv_ws)
{
    const int h = blockIdx.x;
    const int b = blockIdx.y;
    const int tid  = threadIdx.x;
    const int lane = tid & 63;
    const int wave = tid >> 6;
    const int tsub = lane >> 4;          // 0..3: which t-row within the wave
    const int dq   = (lane & 15) << 2;   // 0..60: float4 column offset

    __shared__ float qs[HDIM];
    __shared__ float sc[TCACHE];
    __shared__ float wvp[4 * HDIM];
    __shared__ float red[4];
    __shared__ float red2[4];

    const size_t cacheoff = (size_t)b * TCACHE * NSTATE + (size_t)h * HDIM;
    const float* kin_b  = kin  + cacheoff;
    const float* vin_b  = vin  + cacheoff;
    float*       kout_b = kout + cacheoff;
    float*       vout_b = vout + cacheoff;

    // q row, with scale^2 = d^-0.5 = 0.125 folded in
    if (tid < HDIM) qs[tid] = q_ws[(size_t)b * NSTATE + h * HDIM + tid] * 0.125f;
    __syncthreads();

    // ---- K pass: shift-copy rows + scores ----
    for (int i = 0; i < TCACHE / 16; ++i) {
        int t = i * 16 + wave * 4 + tsub;
        const float* src = (t < TCACHE - 1)
                         ? (kin_b + (size_t)(t + 1) * NSTATE + dq)
                         : (kout_b + (size_t)t * NSTATE + dq);   // row 447: already final
        float4 kv = *(const float4*)src;
        if (t < TCACHE - 1)
            *(float4*)(kout_b + (size_t)t * NSTATE + dq) = kv;
        float p = kv.x * qs[dq] + kv.y * qs[dq+1] + kv.z * qs[dq+2] + kv.w * qs[dq+3];
        p += __shfl_xor(p, 1); p += __shfl_xor(p, 2);
        p += __shfl_xor(p, 4); p += __shfl_xor(p, 8);
        if ((lane & 15) == 0) sc[t] = p + mask[t];
    }
    __syncthreads();

    // ---- softmax over sc[0..447] ----
    float v0 = sc[tid];
    float v1 = (tid + 256 < TCACHE) ? sc[tid + 256] : -1e30f;
    float mx = fmaxf(v0, v1);
    #pragma unroll
    for (int m = 1; m <= 32; m <<= 1) mx = fmaxf(mx, __shfl_xor(mx, m));
    if (lane == 0) red[wave] = mx;
    __syncthreads();
    mx = fmaxf(fmaxf(red[0], red[1]), fmaxf(red[2], red[3]));
    float e0 = __expf(v0 - mx);
    float e1 = (tid + 256 < TCACHE) ? __expf(v1 - mx) : 0.f;
    sc[tid] = e0;
    if (tid + 256 < TCACHE) sc[tid + 256] = e1;
    float s = e0 + e1;
    #pragma unroll
    for (int m = 1; m <= 32; m <<= 1) s += __shfl_xor(s, m);
    if (lane == 0) red2[wave] = s;
    __syncthreads();
    const float inv = 1.0f / (red2[0] + red2[1] + red2[2] + red2[3]);

    // ---- V pass: shift-copy rows + PV accumulate (unnormalized) ----
    float ax = 0.f, ay = 0.f, az = 0.f, aw = 0.f;
    for (int i = 0; i < TCACHE / 16; ++i) {
        int t = i * 16 + wave * 4 + tsub;
        const float* src = (t < TCACHE - 1)
                         ? (vin_b + (size_t)(t + 1) * NSTATE + dq)
                         : (vout_b + (size_t)t * NSTATE + dq);
        float4 vv = *(const float4*)src;
        if (t < TCACHE - 1)
            *(float4*)(vout_b + (size_t)t * NSTATE + dq) = vv;
        float w = sc[t];
        ax = fmaf(w, vv.x, ax); ay = fmaf(w, vv.y, ay);
        az = fmaf(w, vv.z, az); aw = fmaf(w, vv.w, aw);
    }
    // reduce over the 4 t-subsets within the wave (lanes same (lane&15))
    ax += __shfl_xor(ax, 16); ax += __shfl_xor(ax, 32);
    ay += __shfl_xor(ay, 16); ay += __shfl_xor(ay, 32);
    az += __shfl_xor(az, 16); az += __shfl_xor(az, 32);
    aw += __shfl_xor(aw, 16); aw += __shfl_xor(aw, 32);
    if (tsub == 0) {
        wvp[wave * HDIM + dq + 0] = ax;
        wvp[wave * HDIM + dq + 1] = ay;
        wvp[wave * HDIM + dq + 2] = az;
        wvp[wave * HDIM + dq + 3] = aw;
    }
    __syncthreads();
    if (tid < HDIM) {
        float r = wvp[tid] + wvp[HDIM + tid] + wvp[2*HDIM + tid] + wvp[3*HDIM + tid];
        wv_ws[(size_t)b * NSTATE + h * HDIM + tid] = r * inv;
    }
}

extern "C" void kernel_launch(void* const* d_in, const int* in_sizes, int n_in,
                              void* d_out, int out_size, void* d_ws, size_t ws_size,
                              hipStream_t stream)
{
    const float* x       = (const float*)d_in[0];
    const float* k_cache = (const float*)d_in[1];
    const float* v_cache = (const float*)d_in[2];
    const float* mask    = (const float*)d_in[3];
    const float* Wq      = (const float*)d_in[4];
    const float* bq      = (const float*)d_in[5];
    const float* Wk      = (const float*)d_in[6];
    const float* Wv      = (const float*)d_in[7];
    const float* bv      = (const float*)d_in[8];
    const float* Wo      = (const float*)d_in[9];
    const float* bo      = (const float*)d_in[10];

    float* out  = (float*)d_out;                                   // [128,1,1280]
    float* kout = out + (size_t)NBATCH * NSTATE;                   // [128,448,1280]
    float* vout = kout + (size_t)NBATCH * TCACHE * NSTATE;         // [128,448,1280]

    float* q_ws  = (float*)d_ws;                                   // [128,1280]
    float* wv_ws = q_ws + (size_t)NBATCH * NSTATE;                 // [128,1280]

    // 1) projections: q -> ws; k,v -> final row (t=447) of output caches
    qkv_kernel<<<dim3(40, 2, 3), 256, 0, stream>>>(x, Wq, bq, Wk, Wv, bv,
                                                   q_ws, kout, vout);
    // 2) fused cache shift + attention
    attn_kernel<<<dim3(NHEAD, NBATCH), 256, 0, stream>>>(k_cache, v_cache, q_ws,
                                                         mask, kout, vout, wv_ws);
    // 3) output projection
    outproj_kernel<<<dim3(40, 2), 256, 0, stream>>>(wv_ws, Wo, bo, out);
}

// Round 2
// 318.202 us; speedup vs baseline: 1.2787x; 1.2787x over previous
//
#include <hip/hip_runtime.h>
#include <cstddef>

#define NSTATE 1280
#define TCACHE 448
#define NBATCH 128
#define NHEAD  20
#define HDIM   64
#define NT     8
#define RPC    (TCACHE / NT)   // 56 rows per chunk

// ---------------------------------------------------------------------------
// fp32 tiled GEMM partial: C[128][1280] += A[128][k-range] @ B[k-range][1280]
// BM=64, BN=32, BK=32, 256 threads, micro-tile 4x2. No bias; compact C.
// ---------------------------------------------------------------------------
__device__ __forceinline__ void gemm_partial(const float* __restrict__ A,
                                             const float* __restrict__ B,
                                             float* __restrict__ C,
                                             int kb, int ke)
{
    __shared__ float As[32][64];   // [k][m]
    __shared__ float Bs[32][32];   // [k][n]
    const int tid = threadIdx.x;
    const int m0 = blockIdx.y * 64;
    const int n0 = blockIdx.x * 32;
    const int tr = tid >> 4;
    const int tc = tid & 15;
    float acc[4][2] = {{0.f,0.f},{0.f,0.f},{0.f,0.f},{0.f,0.f}};

    for (int k0 = kb; k0 < ke; k0 += 32) {
        #pragma unroll
        for (int j = 0; j < 2; ++j) {
            int chunk = tid * 2 + j;
            int row   = chunk >> 3;
            int kc    = (chunk & 7) << 2;
            float4 a = *(const float4*)(A + (size_t)(m0 + row) * NSTATE + k0 + kc);
            As[kc+0][row] = a.x; As[kc+1][row] = a.y;
            As[kc+2][row] = a.z; As[kc+3][row] = a.w;
        }
        {
            int row = tid >> 3;
            int nc  = (tid & 7) << 2;
            float4 b4 = *(const float4*)(B + (size_t)(k0 + row) * NSTATE + n0 + nc);
            *(float4*)&Bs[row][nc] = b4;
        }
        __syncthreads();
        #pragma unroll
        for (int kk = 0; kk < 32; ++kk) {
            float4 a = *(const float4*)&As[kk][tr << 2];
            float2 b = *(const float2*)&Bs[kk][tc << 1];
            acc[0][0] = fmaf(a.x, b.x, acc[0][0]); acc[0][1] = fmaf(a.x, b.y, acc[0][1]);
            acc[1][0] = fmaf(a.y, b.x, acc[1][0]); acc[1][1] = fmaf(a.y, b.y, acc[1][1]);
            acc[2][0] = fmaf(a.z, b.x, acc[2][0]); acc[2][1] = fmaf(a.z, b.y, acc[2][1]);
            acc[3][0] = fmaf(a.w, b.x, acc[3][0]); acc[3][1] = fmaf(a.w, b.y, acc[3][1]);
        }
        __syncthreads();
    }
    const int n = n0 + (tc << 1);
    #pragma unroll
    for (int i = 0; i < 4; ++i) {
        size_t m = (size_t)(m0 + (tr << 2) + i);
        C[m * NSTATE + n]     = acc[i][0];
        C[m * NSTATE + n + 1] = acc[i][1];
    }
}

// q/k/v projection partials. grid (40, 2, 6): z = mat*2 + split (K split 2x640).
__global__ void __launch_bounds__(256) proj_kernel(
    const float* __restrict__ x,
    const float* __restrict__ Wq, const float* __restrict__ Wk,
    const float* __restrict__ Wv, float* __restrict__ pp)
{
    const int z = blockIdx.z;
    const int mat = z >> 1, sp = z & 1;
    const float* B = (mat == 0) ? Wq : (mat == 1 ? Wk : Wv);
    gemm_partial(x, B, pp + (size_t)z * NBATCH * NSTATE, sp * 640, sp * 640 + 640);
}

// combine split-K partials + bias; scatter q->ws (pre-scaled), k/v -> row 447.
__global__ void __launch_bounds__(256) proj_reduce_kernel(
    const float* __restrict__ pp, const float* __restrict__ bq,
    const float* __restrict__ bv, float* __restrict__ q_ws,
    float* __restrict__ kout, float* __restrict__ vout)
{
    const int mat = blockIdx.y;
    const size_t idx = ((size_t)blockIdx.x * 256 + threadIdx.x) * 4;
    const int b = (int)(idx / NSTATE), col = (int)(idx % NSTATE);
    const float* p0 = pp + (size_t)(mat * 2) * NBATCH * NSTATE + idx;
    const float* p1 = p0 + (size_t)NBATCH * NSTATE;
    float4 a = *(const float4*)p0, c = *(const float4*)p1;
    float4 v = make_float4(a.x + c.x, a.y + c.y, a.z + c.z, a.w + c.w);
    if (mat == 0) {
        float4 bb = *(const float4*)(bq + col);
        v.x = (v.x + bb.x) * 0.125f; v.y = (v.y + bb.y) * 0.125f;
        v.z = (v.z + bb.z) * 0.125f; v.w = (v.w + bb.w) * 0.125f;
        *(float4*)(q_ws + idx) = v;
    } else if (mat == 1) {
        *(float4*)(kout + ((size_t)b * TCACHE + TCACHE - 1) * NSTATE + col) = v;
    } else {
        float4 bb = *(const float4*)(bv + col);
        v.x += bb.x; v.y += bb.y; v.z += bb.z; v.w += bb.w;
        *(float4*)(vout + ((size_t)b * TCACHE + TCACHE - 1) * NSTATE + col) = v;
    }
}

// ---------------------------------------------------------------------------
// K stream: contiguous row copy (shift) + all-head scores.
// grid (NT, 128), 320 threads: thread = one float4 column slot of a row,
// head = tid>>4. Rows stream contiguously (5120 B per iteration per block).
// ---------------------------------------------------------------------------
__global__ void __launch_bounds__(320) scorek_kernel(
    const float* __restrict__ kin, const float* __restrict__ q_ws,
    const float* __restrict__ mask, float* __restrict__ kout,
    float* __restrict__ sc_ws)
{
    const int tc = blockIdx.x, b = blockIdx.y;
    const int tid = threadIdx.x;
    const int h = tid >> 4;
    const int col = tid << 2;
    const size_t base = (size_t)b * TCACHE * NSTATE;
    const float4 q4 = *(const float4*)(q_ws + (size_t)b * NSTATE + col);
    const int t0 = tc * RPC;
    #pragma unroll 4
    for (int r = 0; r < RPC; ++r) {
        const int t = t0 + r;
        const float* src = (t < TCACHE - 1)
            ? kin  + base + (size_t)(t + 1) * NSTATE + col
            : kout + base + (size_t)t * NSTATE + col;   // row 447 already final
        float4 kv = *(const float4*)src;
        if (t < TCACHE - 1)
            *(float4*)(kout + base + (size_t)t * NSTATE + col) = kv;
        float p = kv.x * q4.x + kv.y * q4.y + kv.z * q4.z + kv.w * q4.w;
        p += __shfl_xor(p, 1); p += __shfl_xor(p, 2);
        p += __shfl_xor(p, 4); p += __shfl_xor(p, 8);
        if ((tid & 15) == 0)
            sc_ws[((size_t)b * NHEAD + h) * TCACHE + t] = p + mask[t];
    }
}

// softmax in place over sc_ws rows of length 448 = 7*64. One wave per (b,h).
__global__ void __launch_bounds__(256) softmax_kernel(float* __restrict__ sc)
{
    const int bh = blockIdx.x * 4 + (threadIdx.x >> 6);
    const int lane = threadIdx.x & 63;
    float* row = sc + (size_t)bh * TCACHE;
    float v[7];
    float m = -1e30f;
    #pragma unroll
    for (int i = 0; i < 7; ++i) { v[i] = row[i * 64 + lane]; m = fmaxf(m, v[i]); }
    #pragma unroll
    for (int d = 1; d <= 32; d <<= 1) m = fmaxf(m, __shfl_xor(m, d));
    float s = 0.f;
    #pragma unroll
    for (int i = 0; i < 7; ++i) { v[i] = __expf(v[i] - m); s += v[i]; }
    #pragma unroll
    for (int d = 1; d <= 32; d <<= 1) s += __shfl_xor(s, d);
    const float inv = 1.0f / s;
    #pragma unroll
    for (int i = 0; i < 7; ++i) row[i * 64 + lane] = v[i] * inv;
}

// ---------------------------------------------------------------------------
// V stream: contiguous row copy (shift) + per-chunk PV partial accumulate.
// ---------------------------------------------------------------------------
__global__ void __launch_bounds__(320) pvv_kernel(
    const float* __restrict__ vin, const float* __restrict__ w_ws,
    float* __restrict__ vout, float* __restrict__ wvp)
{
    const int tc = blockIdx.x, b = blockIdx.y;
    const int tid = threadIdx.x;
    const int h = tid >> 4;
    const int col = tid << 2;
    const int t0 = tc * RPC;
    __shared__ float wl[NHEAD * RPC];
    for (int i = tid; i < NHEAD * RPC; i += 320) {
        int hh = i / RPC, rr = i - hh * RPC;
        wl[i] = w_ws[((size_t)b * NHEAD + hh) * TCACHE + t0 + rr];
    }
    __syncthreads();
    const size_t base = (size_t)b * TCACHE * NSTATE;
    float4 acc = make_float4(0.f, 0.f, 0.f, 0.f);
    #pragma unroll 4
    for (int r = 0; r < RPC; ++r) {
        const int t = t0 + r;
        const float* src = (t < TCACHE - 1)
            ? vin  + base + (size_t)(t + 1) * NSTATE + col
            : vout + base + (size_t)t * NSTATE + col;
        float4 vv = *(const float4*)src;
        if (t < TCACHE - 1)
            *(float4*)(vout + base + (size_t)t * NSTATE + col) = vv;
        const float w = wl[h * RPC + r];
        acc.x = fmaf(w, vv.x, acc.x); acc.y = fmaf(w, vv.y, acc.y);
        acc.z = fmaf(w, vv.z, acc.z); acc.w = fmaf(w, vv.w, acc.w);
    }
    *(float4*)(wvp + ((size_t)b * NT + tc) * NSTATE + col) = acc;
}

// sum the NT chunk partials -> wv [128][1280]
__global__ void __launch_bounds__(256) wv_reduce_kernel(
    const float* __restrict__ wvp, float* __restrict__ wv_ws)
{
    const size_t idx = ((size_t)blockIdx.x * 256 + threadIdx.x) * 4;
    const int b = (int)(idx / NSTATE), col = (int)(idx % NSTATE);
    float4 s = make_float4(0.f, 0.f, 0.f, 0.f);
    #pragma unroll
    for (int c = 0; c < NT; ++c) {
        float4 a = *(const float4*)(wvp + ((size_t)b * NT + c) * NSTATE + col);
        s.x += a.x; s.y += a.y; s.z += a.z; s.w += a.w;
    }
    *(float4*)(wv_ws + idx) = s;
}

// output projection partials. grid (40, 2, 4): z = split (K split 4x320).
__global__ void __launch_bounds__(256) outproj_kernel(
    const float* __restrict__ wv, const float* __restrict__ Wo,
    float* __restrict__ po)
{
    const int sp = blockIdx.z;
    gemm_partial(wv, Wo, po + (size_t)sp * NBATCH * NSTATE, sp * 320, sp * 320 + 320);
}

__global__ void __launch_bounds__(256) out_reduce_kernel(
    const float* __restrict__ po, const float* __restrict__ bo,
    float* __restrict__ out)
{
    const size_t idx = ((size_t)blockIdx.x * 256 + threadIdx.x) * 4;
    const int col = (int)(idx % NSTATE);
    float4 s = *(const float4*)(bo + col);
    #pragma unroll
    for (int c = 0; c < 4; ++c) {
        float4 a = *(const float4*)(po + (size_t)c * NBATCH * NSTATE + idx);
        s.x += a.x; s.y += a.y; s.z += a.z; s.w += a.w;
    }
    *(float4*)(out + idx) = s;
}

extern "C" void kernel_launch(void* const* d_in, const int* in_sizes, int n_in,
                              void* d_out, int out_size, void* d_ws, size_t ws_size,
                              hipStream_t stream)
{
    const float* x       = (const float*)d_in[0];
    const float* k_cache = (const float*)d_in[1];
    const float* v_cache = (const float*)d_in[2];
    const float* mask    = (const float*)d_in[3];
    const float* Wq      = (const float*)d_in[4];
    const float* bq      = (const float*)d_in[5];
    const float* Wk      = (const float*)d_in[6];
    const float* Wv      = (const float*)d_in[7];
    const float* bv      = (const float*)d_in[8];
    const float* Wo      = (const float*)d_in[9];
    const float* bo      = (const float*)d_in[10];

    float* out  = (float*)d_out;                                   // [128,1,1280]
    float* kout = out + (size_t)NBATCH * NSTATE;                   // [128,448,1280]
    float* vout = kout + (size_t)NBATCH * TCACHE * NSTATE;         // [128,448,1280]

    float* ws     = (float*)d_ws;
    float* q_ws   = ws;                                            // 163840
    float* sc_ws  = q_ws  + (size_t)NBATCH * NSTATE;               // 1146880
    float* wvp_ws = sc_ws + (size_t)NBATCH * NHEAD * TCACHE;       // 1310720
    float* pp_ws  = wvp_ws + (size_t)NBATCH * NT * NSTATE;         // 983040
    float* po_ws  = pp_ws + (size_t)6 * NBATCH * NSTATE;           // 655360
    float* wv_ws  = po_ws + (size_t)4 * NBATCH * NSTATE;           // 163840

    // 1) q/k/v projection (split-K) -> partials; reduce scatters k/v row 447
    proj_kernel<<<dim3(40, 2, 6), 256, 0, stream>>>(x, Wq, Wk, Wv, pp_ws);
    proj_reduce_kernel<<<dim3(160, 3), 256, 0, stream>>>(pp_ws, bq, bv,
                                                         q_ws, kout, vout);
    // 2) K stream: shift-copy + scores
    scorek_kernel<<<dim3(NT, NBATCH), 320, 0, stream>>>(k_cache, q_ws, mask,
                                                        kout, sc_ws);
    // 3) softmax (in place)
    softmax_kernel<<<dim3(NBATCH * NHEAD / 4), 256, 0, stream>>>(sc_ws);
    // 4) V stream: shift-copy + PV partials
    pvv_kernel<<<dim3(NT, NBATCH), 320, 0, stream>>>(v_cache, sc_ws, vout, wvp_ws);
    wv_reduce_kernel<<<dim3(160), 256, 0, stream>>>(wvp_ws, wv_ws);
    // 5) output projection (split-K) + reduce with bias
    outproj_kernel<<<dim3(40, 2, 4), 256, 0, stream>>>(wv_ws, Wo, po_ws);
    out_reduce_kernel<<<dim3(160), 256, 0, stream>>>(po_ws, bo, out);
}

// Round 3
// 317.601 us; speedup vs baseline: 1.2812x; 1.0019x over previous
//
#include <hip/hip_runtime.h>
#include <cstddef>

#define NSTATE 1280
#define TCACHE 448
#define NBATCH 128
#define NHEAD  20
#define HDIM   64
#define NT     8
#define RPC    (TCACHE / NT)   // 56 rows per chunk

typedef float f4 __attribute__((ext_vector_type(4)));

// ---------------------------------------------------------------------------
// fp32 tiled GEMM: C[m][n] = (A[128][1280] @ B[kb:ke][1280] + bias) * scale
// BM=64, BN=32, BK=32, 256 threads, micro-tile 4x2. ldc parameterized so k/v
// projections write directly into row 447 of the output caches.
// ---------------------------------------------------------------------------
__device__ __forceinline__ void gemm_body(const float* __restrict__ A,
                                          const float* __restrict__ B,
                                          const float* __restrict__ bias,
                                          float* __restrict__ C, size_t ldc,
                                          int kb, int ke, float scale)
{
    __shared__ float As[32][64];   // [k][m]
    __shared__ float Bs[32][32];   // [k][n]
    const int tid = threadIdx.x;
    const int m0 = blockIdx.y * 64;
    const int n0 = blockIdx.x * 32;
    const int tr = tid >> 4;
    const int tc = tid & 15;
    float acc[4][2] = {{0.f,0.f},{0.f,0.f},{0.f,0.f},{0.f,0.f}};

    for (int k0 = kb; k0 < ke; k0 += 32) {
        #pragma unroll
        for (int j = 0; j < 2; ++j) {
            int chunk = tid * 2 + j;
            int row   = chunk >> 3;
            int kc    = (chunk & 7) << 2;
            float4 a = *(const float4*)(A + (size_t)(m0 + row) * NSTATE + k0 + kc);
            As[kc+0][row] = a.x; As[kc+1][row] = a.y;
            As[kc+2][row] = a.z; As[kc+3][row] = a.w;
        }
        {
            int row = tid >> 3;
            int nc  = (tid & 7) << 2;
            float4 b4 = *(const float4*)(B + (size_t)(k0 + row) * NSTATE + n0 + nc);
            *(float4*)&Bs[row][nc] = b4;
        }
        __syncthreads();
        #pragma unroll
        for (int kk = 0; kk < 32; ++kk) {
            float4 a = *(const float4*)&As[kk][tr << 2];
            float2 b = *(const float2*)&Bs[kk][tc << 1];
            acc[0][0] = fmaf(a.x, b.x, acc[0][0]); acc[0][1] = fmaf(a.x, b.y, acc[0][1]);
            acc[1][0] = fmaf(a.y, b.x, acc[1][0]); acc[1][1] = fmaf(a.y, b.y, acc[1][1]);
            acc[2][0] = fmaf(a.z, b.x, acc[2][0]); acc[2][1] = fmaf(a.z, b.y, acc[2][1]);
            acc[3][0] = fmaf(a.w, b.x, acc[3][0]); acc[3][1] = fmaf(a.w, b.y, acc[3][1]);
        }
        __syncthreads();
    }
    const int n = n0 + (tc << 1);
    const float b0 = bias ? bias[n]   : 0.f;
    const float b1 = bias ? bias[n+1] : 0.f;
    #pragma unroll
    for (int i = 0; i < 4; ++i) {
        size_t m = (size_t)(m0 + (tr << 2) + i);
        C[m * ldc + n]     = (acc[i][0] + b0) * scale;
        C[m * ldc + n + 1] = (acc[i][1] + b1) * scale;
    }
}

// q/k/v projection, direct write. grid (40, 2, 3): z=0 q (scaled, ->ws),
// z=1 k -> row 447 kout (no bias), z=2 v -> row 447 vout.
__global__ void __launch_bounds__(256) proj_qkv_kernel(
    const float* __restrict__ x,
    const float* __restrict__ Wq, const float* __restrict__ bq,
    const float* __restrict__ Wk,
    const float* __restrict__ Wv, const float* __restrict__ bv,
    float* __restrict__ q_ws, float* __restrict__ kout, float* __restrict__ vout)
{
    const int z = blockIdx.z;
    if (z == 0) {
        gemm_body(x, Wq, bq, q_ws, NSTATE, 0, NSTATE, 0.125f);       // both scales folded
    } else if (z == 1) {
        gemm_body(x, Wk, nullptr, kout + (size_t)(TCACHE-1) * NSTATE,
                  (size_t)TCACHE * NSTATE, 0, NSTATE, 1.0f);
    } else {
        gemm_body(x, Wv, bv, vout + (size_t)(TCACHE-1) * NSTATE,
                  (size_t)TCACHE * NSTATE, 0, NSTATE, 1.0f);
    }
}

// ---------------------------------------------------------------------------
// K stream: contiguous nt row copy (shift) + all-head raw scores.
// grid (NT, 128), 320 threads: thread = one float4 slot of a row, h = tid>>4.
// ---------------------------------------------------------------------------
__global__ void __launch_bounds__(320) scorek_kernel(
    const float* __restrict__ kin, const float* __restrict__ q_ws,
    const float* __restrict__ mask, float* __restrict__ kout,
    float* __restrict__ sc_ws)
{
    const int tc = blockIdx.x, b = blockIdx.y;
    const int tid = threadIdx.x;
    const int h = tid >> 4;
    const int col = tid << 2;
    const size_t base = (size_t)b * TCACHE * NSTATE;
    const float4 q4 = *(const float4*)(q_ws + (size_t)b * NSTATE + col);
    const int t0 = tc * RPC;
    const int nrows = (tc == NT - 1) ? RPC - 1 : RPC;
    const float* src0 = kin + base + (size_t)(t0 + 1) * NSTATE + col;
    float* dst0 = kout + base + (size_t)t0 * NSTATE + col;
    float* scrow = sc_ws + ((size_t)b * NHEAD + h) * TCACHE + t0;

    #pragma unroll 4
    for (int r = 0; r < nrows; ++r) {
        f4 kv = __builtin_nontemporal_load((const f4*)(src0 + (size_t)r * NSTATE));
        __builtin_nontemporal_store(kv, (f4*)(dst0 + (size_t)r * NSTATE));
        float p = kv[0]*q4.x + kv[1]*q4.y + kv[2]*q4.z + kv[3]*q4.w;
        p += __shfl_xor(p, 1); p += __shfl_xor(p, 2);
        p += __shfl_xor(p, 4); p += __shfl_xor(p, 8);
        if ((tid & 15) == 0) scrow[r] = p + mask[t0 + r];
    }
    if (tc == NT - 1) {                       // row 447: already final in kout
        const f4 kv = *(const f4*)(kout + base + (size_t)(TCACHE-1) * NSTATE + col);
        float p = kv[0]*q4.x + kv[1]*q4.y + kv[2]*q4.z + kv[3]*q4.w;
        p += __shfl_xor(p, 1); p += __shfl_xor(p, 2);
        p += __shfl_xor(p, 4); p += __shfl_xor(p, 8);
        if ((tid & 15) == 0) scrow[RPC - 1] = p + mask[TCACHE - 1];
    }
}

// ---------------------------------------------------------------------------
// V stream: per-head softmax stats (from raw scores in L2) + contiguous nt
// row copy (shift) + per-chunk PV partial accumulate.
// ---------------------------------------------------------------------------
__global__ void __launch_bounds__(320) pvv_kernel(
    const float* __restrict__ vin, const float* __restrict__ sc_ws,
    float* __restrict__ vout, float* __restrict__ wvp)
{
    const int tc = blockIdx.x, b = blockIdx.y;
    const int tid = threadIdx.x;
    const int h = tid >> 4, l = tid & 15;
    const int col = tid << 2;
    const int t0 = tc * RPC;
    __shared__ float wl[NHEAD * RPC];

    // softmax stats over the full row (448 = 16 lanes x 28)
    const float* row = sc_ws + ((size_t)b * NHEAD + h) * TCACHE;
    float v[28];
    float m = -1e30f;
    #pragma unroll
    for (int j = 0; j < 28; ++j) { v[j] = row[l + 16*j]; m = fmaxf(m, v[j]); }
    #pragma unroll
    for (int d = 1; d <= 8; d <<= 1) m = fmaxf(m, __shfl_xor(m, d));
    float s = 0.f;
    #pragma unroll
    for (int j = 0; j < 28; ++j) s += __expf(v[j] - m);
    #pragma unroll
    for (int d = 1; d <= 8; d <<= 1) s += __shfl_xor(s, d);
    const float inv = 1.0f / s;
    #pragma unroll
    for (int j = 0; j < 4; ++j) {
        int r = l + 16*j;
        if (r < RPC) wl[h * RPC + r] = __expf(row[t0 + r] - m) * inv;
    }
    __syncthreads();

    const size_t base = (size_t)b * TCACHE * NSTATE;
    const int nrows = (tc == NT - 1) ? RPC - 1 : RPC;
    const float* src0 = vin + base + (size_t)(t0 + 1) * NSTATE + col;
    float* dst0 = vout + base + (size_t)t0 * NSTATE + col;
    float ax = 0.f, ay = 0.f, az = 0.f, aw = 0.f;
    #pragma unroll 4
    for (int r = 0; r < nrows; ++r) {
        f4 vv = __builtin_nontemporal_load((const f4*)(src0 + (size_t)r * NSTATE));
        __builtin_nontemporal_store(vv, (f4*)(dst0 + (size_t)r * NSTATE));
        const float w = wl[h * RPC + r];
        ax = fmaf(w, vv[0], ax); ay = fmaf(w, vv[1], ay);
        az = fmaf(w, vv[2], az); aw = fmaf(w, vv[3], aw);
    }
    if (tc == NT - 1) {                       // row 447: already final in vout
        const f4 vv = *(const f4*)(vout + base + (size_t)(TCACHE-1) * NSTATE + col);
        const float w = wl[h * RPC + RPC - 1];
        ax = fmaf(w, vv[0], ax); ay = fmaf(w, vv[1], ay);
        az = fmaf(w, vv[2], az); aw = fmaf(w, vv[3], aw);
    }
    *(float4*)(wvp + ((size_t)b * NT + tc) * NSTATE + col) =
        make_float4(ax, ay, az, aw);
}

// sum the NT chunk partials -> wv [128][1280]
__global__ void __launch_bounds__(256) wv_reduce_kernel(
    const float* __restrict__ wvp, float* __restrict__ wv_ws)
{
    const size_t idx = ((size_t)blockIdx.x * 256 + threadIdx.x) * 4;
    const int b = (int)(idx / NSTATE), col = (int)(idx % NSTATE);
    float4 s = make_float4(0.f, 0.f, 0.f, 0.f);
    #pragma unroll
    for (int c = 0; c < NT; ++c) {
        float4 a = *(const float4*)(wvp + ((size_t)b * NT + c) * NSTATE + col);
        s.x += a.x; s.y += a.y; s.z += a.z; s.w += a.w;
    }
    *(float4*)(wv_ws + idx) = s;
}

// output projection partials. grid (40, 2, 4): z = K-split (4 x 320).
__global__ void __launch_bounds__(256) outproj_kernel(
    const float* __restrict__ wv, const float* __restrict__ Wo,
    float* __restrict__ po)
{
    const int sp = blockIdx.z;
    gemm_body(wv, Wo, nullptr, po + (size_t)sp * NBATCH * NSTATE,
              NSTATE, sp * 320, sp * 320 + 320, 1.0f);
}

__global__ void __launch_bounds__(256) out_reduce_kernel(
    const float* __restrict__ po, const float* __restrict__ bo,
    float* __restrict__ out)
{
    const size_t idx = ((size_t)blockIdx.x * 256 + threadIdx.x) * 4;
    const int col = (int)(idx % NSTATE);
    float4 s = *(const float4*)(bo + col);
    #pragma unroll
    for (int c = 0; c < 4; ++c) {
        float4 a = *(const float4*)(po + (size_t)c * NBATCH * NSTATE + idx);
        s.x += a.x; s.y += a.y; s.z += a.z; s.w += a.w;
    }
    *(float4*)(out + idx) = s;
}

extern "C" void kernel_launch(void* const* d_in, const int* in_sizes, int n_in,
                              void* d_out, int out_size, void* d_ws, size_t ws_size,
                              hipStream_t stream)
{
    const float* x       = (const float*)d_in[0];
    const float* k_cache = (const float*)d_in[1];
    const float* v_cache = (const float*)d_in[2];
    const float* mask    = (const float*)d_in[3];
    const float* Wq      = (const float*)d_in[4];
    const float* bq      = (const float*)d_in[5];
    const float* Wk      = (const float*)d_in[6];
    const float* Wv      = (const float*)d_in[7];
    const float* bv      = (const float*)d_in[8];
    const float* Wo      = (const float*)d_in[9];
    const float* bo      = (const float*)d_in[10];

    float* out  = (float*)d_out;                                   // [128,1,1280]
    float* kout = out + (size_t)NBATCH * NSTATE;                   // [128,448,1280]
    float* vout = kout + (size_t)NBATCH * TCACHE * NSTATE;         // [128,448,1280]

    float* ws     = (float*)d_ws;
    float* q_ws   = ws;                                            // 163840
    float* sc_ws  = q_ws  + (size_t)NBATCH * NSTATE;               // 1146880
    float* wvp_ws = sc_ws + (size_t)NBATCH * NHEAD * TCACHE;       // 1310720
    float* po_ws  = wvp_ws + (size_t)NBATCH * NT * NSTATE;         // 655360
    float* wv_ws  = po_ws + (size_t)4 * NBATCH * NSTATE;           // 163840

    // 1) q/k/v projection: q -> ws (pre-scaled); k,v -> row 447 of out caches
    proj_qkv_kernel<<<dim3(40, 2, 3), 256, 0, stream>>>(x, Wq, bq, Wk, Wv, bv,
                                                        q_ws, kout, vout);
    // 2) K stream: nt shift-copy + raw scores
    scorek_kernel<<<dim3(NT, NBATCH), 320, 0, stream>>>(k_cache, q_ws, mask,
                                                        kout, sc_ws);
    // 3) V stream: softmax-on-the-fly + nt shift-copy + PV partials
    pvv_kernel<<<dim3(NT, NBATCH), 320, 0, stream>>>(v_cache, sc_ws, vout, wvp_ws);
    wv_reduce_kernel<<<dim3(160), 256, 0, stream>>>(wvp_ws, wv_ws);
    // 4) output projection (split-K) + reduce with bias
    outproj_kernel<<<dim3(40, 2, 4), 256, 0, stream>>>(wv_ws, Wo, po_ws);
    out_reduce_kernel<<<dim3(160), 256, 0, stream>>>(po_ws, bo, out);
}